// Round 1
// baseline (20.205 us; speedup 1.0000x reference)
//
#include <hip/hip_runtime.h>
#include <math.h>

// Fused SPDS extractor:
//   for p in {2,4,8}: sliding p×p patches (stride p/2) -> per-patch mean,
//   std(ddof=1)+1e-6, and (p==2) channel-mean of sign(det)*|det|^0.7,
//   each plane bilinear-resized (align_corners=False) to 32x32.
// Fusion: bilinear downsample touches only 2x2 source positions per output
// pixel, so we compute the 4 corner-patch stats on the fly and blend —
// no intermediate n×n planes, no workspace.
//
// Thread map: tid -> (b, oy, ox, corner); corner = tid&3 so the 4 corners of
// one output pixel sit in lanes {4k..4k+3}; combined via __shfl_xor(1/2).

template <int P>
__device__ __forceinline__ void patch_stats(const float* __restrict__ xc,
                                            float& mean, float& stdv, float& rawdet) {
    constexpr int PP = P * P;
    float s = 0.0f, ss = 0.0f;
    rawdet = 0.0f;
    if constexpr (P == 2) {
        float a = xc[0], b = xc[1], c = xc[256], d = xc[257];
        s  = a + b + c + d;
        ss = a*a + b*b + c*c + d*d;
        rawdet = a*d - b*c;
    } else if constexpr (P == 4) {
        // col0 = 2*ix -> 8B aligned: float2 loads are safe
        #pragma unroll
        for (int dy = 0; dy < 4; ++dy) {
            const float2* r = reinterpret_cast<const float2*>(xc + dy * 256);
            float2 u = r[0], v = r[1];
            s  += u.x + u.y + v.x + v.y;
            ss += u.x*u.x + u.y*u.y + v.x*v.x + v.y*v.y;
        }
    } else {  // P == 8
        // col0 = 4*ix -> 16B aligned: float4 loads are safe
        #pragma unroll
        for (int dy = 0; dy < 8; ++dy) {
            const float4* r = reinterpret_cast<const float4*>(xc + dy * 256);
            float4 u = r[0], v = r[1];
            s  += u.x + u.y + u.z + u.w + v.x + v.y + v.z + v.w;
            ss += u.x*u.x + u.y*u.y + u.z*u.z + u.w*u.w
                + v.x*v.x + v.y*v.y + v.z*v.z + v.w*v.w;
        }
    }
    mean = s * (1.0f / PP);
    float var = (ss - s * s * (1.0f / PP)) * (1.0f / (PP - 1));
    stdv = sqrtf(fmaxf(var, 0.0f)) + 1e-6f;
}

template <int P, int CHBASE>
__global__ __launch_bounds__(256) void spds_kernel(const float* __restrict__ x,
                                                   float* __restrict__ out,
                                                   int B) {
    constexpr int STRIDE = P / 2;
    constexpr int N = (256 - P) / STRIDE + 1;   // 255 / 127 / 63
    constexpr int NV = (P == 2) ? 7 : 6;

    int tid    = blockIdx.x * 256 + threadIdx.x;
    int corner = tid & 3;
    int t      = tid >> 2;
    int ox     = t & 31;
    int oy     = (t >> 5) & 31;
    int b      = t >> 10;
    if (b >= B) return;

    // bilinear source coords, align_corners=False (exact f32 match: N/32 is
    // a power-of-two-denominator rational, exact in f32)
    const float scale = (float)N / 32.0f;
    float sy = (oy + 0.5f) * scale - 0.5f;
    sy = fminf(fmaxf(sy, 0.0f), (float)(N - 1));
    int   yl = (int)floorf(sy);
    int   yh = min(yl + 1, N - 1);
    float wy = sy - (float)yl;

    float sx = (ox + 0.5f) * scale - 0.5f;
    sx = fminf(fmaxf(sx, 0.0f), (float)(N - 1));
    int   xl = (int)floorf(sx);
    int   xh = min(xl + 1, N - 1);
    float wx = sx - (float)xl;

    int   iy = (corner & 2) ? yh : yl;
    int   ix = (corner & 1) ? xh : xl;
    float w  = ((corner & 2) ? wy : 1.0f - wy) * ((corner & 1) ? wx : 1.0f - wx);

    int row0 = iy * STRIDE;
    int col0 = ix * STRIDE;
    const float* xb = x + (size_t)b * 3 * 256 * 256 + row0 * 256 + col0;

    float vals[7];
    float det = 0.0f;
    #pragma unroll
    for (int c = 0; c < 3; ++c) {
        float mean, stdv, raw;
        patch_stats<P>(xb + (size_t)c * 256 * 256, mean, stdv, raw);
        vals[c]     = mean * w;
        vals[3 + c] = stdv * w;
        if constexpr (P == 2) {
            det += copysignf(powf(fabsf(raw), 0.7f), raw);
        }
    }
    if constexpr (P == 2) {
        vals[6] = det * (1.0f / 3.0f) * w;
    }

    // combine the 4 corners (lanes 4k..4k+3)
    #pragma unroll
    for (int i = 0; i < NV; ++i) {
        float v = vals[i];
        v += __shfl_xor(v, 1);
        v += __shfl_xor(v, 2);
        vals[i] = v;
    }

    if (corner == 0) {
        float* ob = out + ((size_t)b * 19 + CHBASE) * 1024 + oy * 32 + ox;
        #pragma unroll
        for (int i = 0; i < NV; ++i)
            ob[(size_t)i * 1024] = vals[i];
    }
}

extern "C" void kernel_launch(void* const* d_in, const int* in_sizes, int n_in,
                              void* d_out, int out_size, void* d_ws, size_t ws_size,
                              hipStream_t stream) {
    const float* x  = (const float*)d_in[0];
    float*       out = (float*)d_out;
    int B = in_sizes[0] / (3 * 256 * 256);       // 32
    int blocks = B * 16;                         // B * 32*32*4 threads / 256

    spds_kernel<2, 0 ><<<blocks, 256, 0, stream>>>(x, out, B);
    spds_kernel<4, 7 ><<<blocks, 256, 0, stream>>>(x, out, B);
    spds_kernel<8, 13><<<blocks, 256, 0, stream>>>(x, out, B);
}

// Round 2
// 14.769 us; speedup vs baseline: 1.3681x; 1.3681x over previous
//
#include <hip/hip_runtime.h>
#include <math.h>

// Fused SPDS extractor, single dispatch:
//   for p in {2,4,8}: sliding p×p patches (stride p/2) -> per-patch mean,
//   std(ddof=1)+1e-6, and (p==2) channel-mean of sign(det)*|det|^0.7,
//   each plane bilinear-resized (align_corners=False) to 32x32.
// Fusion 1: bilinear downsample touches only 2x2 source patch positions per
//   output pixel -> compute the 4 corner-patch stats on the fly and blend.
// Fusion 2: all three scales in ONE kernel launch; block ranges pick P.
//   Heavy P=8 blocks first so they start earliest; whole grid (1536 blocks,
//   393K threads) is co-resident on 256 CUs, so scales run concurrently.
//
// Thread map: tid -> (b, oy, ox, corner); corner = tid&3 so the 4 corners of
// one output pixel sit in lanes {4k..4k+3}; combined via __shfl_xor(1/2).

template <int P>
__device__ __forceinline__ void patch_stats(const float* __restrict__ xc,
                                            float& mean, float& stdv, float& rawdet) {
    constexpr int PP = P * P;
    float s = 0.0f, ss = 0.0f;
    rawdet = 0.0f;
    if constexpr (P == 2) {
        float a = xc[0], b = xc[1], c = xc[256], d = xc[257];
        s  = a + b + c + d;
        ss = a*a + b*b + c*c + d*d;
        rawdet = a*d - b*c;
    } else if constexpr (P == 4) {
        // col0 = 2*ix -> 8B aligned: float2 loads are safe
        #pragma unroll
        for (int dy = 0; dy < 4; ++dy) {
            const float2* r = reinterpret_cast<const float2*>(xc + dy * 256);
            float2 u = r[0], v = r[1];
            s  += u.x + u.y + v.x + v.y;
            ss += u.x*u.x + u.y*u.y + v.x*v.x + v.y*v.y;
        }
    } else {  // P == 8
        // col0 = 4*ix -> 16B aligned: float4 loads are safe
        #pragma unroll
        for (int dy = 0; dy < 8; ++dy) {
            const float4* r = reinterpret_cast<const float4*>(xc + dy * 256);
            float4 u = r[0], v = r[1];
            s  += u.x + u.y + u.z + u.w + v.x + v.y + v.z + v.w;
            ss += u.x*u.x + u.y*u.y + u.z*u.z + u.w*u.w
                + v.x*v.x + v.y*v.y + v.z*v.z + v.w*v.w;
        }
    }
    mean = s * (1.0f / PP);
    float var = (ss - s * s * (1.0f / PP)) * (1.0f / (PP - 1));
    stdv = sqrtf(fmaxf(var, 0.0f)) + 1e-6f;
}

// sign(x)*|x|^0.7 via hardware exp2/log2 (abs threshold 5.7e-2 >> error)
__device__ __forceinline__ float signed_pow07(float raw) {
    float a = fabsf(raw);
    float r = exp2f(0.7f * log2f(fmaxf(a, 1e-38f)));   // a==0 -> ~3e-27 ~ 0
    return copysignf(r, raw);
}

template <int P, int CHBASE>
__device__ __forceinline__ void spds_scale(const float* __restrict__ x,
                                           float* __restrict__ out,
                                           int tid) {
    constexpr int STRIDE = P / 2;
    constexpr int N = (256 - P) / STRIDE + 1;   // 255 / 127 / 63
    constexpr int NV = (P == 2) ? 7 : 6;

    int corner = tid & 3;
    int t      = tid >> 2;
    int ox     = t & 31;
    int oy     = (t >> 5) & 31;
    int b      = t >> 10;

    // bilinear source coords, align_corners=False
    const float scale = (float)N / 32.0f;
    float sy = (oy + 0.5f) * scale - 0.5f;
    sy = fminf(fmaxf(sy, 0.0f), (float)(N - 1));
    int   yl = (int)floorf(sy);
    int   yh = min(yl + 1, N - 1);
    float wy = sy - (float)yl;

    float sx = (ox + 0.5f) * scale - 0.5f;
    sx = fminf(fmaxf(sx, 0.0f), (float)(N - 1));
    int   xl = (int)floorf(sx);
    int   xh = min(xl + 1, N - 1);
    float wx = sx - (float)xl;

    int   iy = (corner & 2) ? yh : yl;
    int   ix = (corner & 1) ? xh : xl;
    float w  = ((corner & 2) ? wy : 1.0f - wy) * ((corner & 1) ? wx : 1.0f - wx);

    int row0 = iy * STRIDE;
    int col0 = ix * STRIDE;
    const float* xb = x + (size_t)b * 3 * 256 * 256 + row0 * 256 + col0;

    float vals[7];
    float det = 0.0f;
    #pragma unroll
    for (int c = 0; c < 3; ++c) {
        float mean, stdv, raw;
        patch_stats<P>(xb + (size_t)c * 256 * 256, mean, stdv, raw);
        vals[c]     = mean * w;
        vals[3 + c] = stdv * w;
        if constexpr (P == 2) {
            det += signed_pow07(raw);
        }
    }
    if constexpr (P == 2) {
        vals[6] = det * (1.0f / 3.0f) * w;
    }

    // combine the 4 corners (lanes 4k..4k+3)
    #pragma unroll
    for (int i = 0; i < NV; ++i) {
        float v = vals[i];
        v += __shfl_xor(v, 1);
        v += __shfl_xor(v, 2);
        vals[i] = v;
    }

    if (corner == 0) {
        float* ob = out + ((size_t)b * 19 + CHBASE) * 1024 + oy * 32 + ox;
        #pragma unroll
        for (int i = 0; i < NV; ++i)
            ob[(size_t)i * 1024] = vals[i];
    }
}

__global__ __launch_bounds__(256) void spds_fused(const float* __restrict__ x,
                                                  float* __restrict__ out,
                                                  int blocksPerScale) {
    int bid = blockIdx.x;
    if (bid < blocksPerScale) {
        // heavy scale first
        int tid = bid * 256 + threadIdx.x;
        spds_scale<8, 13>(x, out, tid);
    } else if (bid < 2 * blocksPerScale) {
        int tid = (bid - blocksPerScale) * 256 + threadIdx.x;
        spds_scale<4, 7>(x, out, tid);
    } else {
        int tid = (bid - 2 * blocksPerScale) * 256 + threadIdx.x;
        spds_scale<2, 0>(x, out, tid);
    }
}

extern "C" void kernel_launch(void* const* d_in, const int* in_sizes, int n_in,
                              void* d_out, int out_size, void* d_ws, size_t ws_size,
                              hipStream_t stream) {
    const float* x   = (const float*)d_in[0];
    float*       out = (float*)d_out;
    int B = in_sizes[0] / (3 * 256 * 256);       // 32
    int blocksPerScale = B * 16;                 // B * 32*32*4 threads / 256
    spds_fused<<<3 * blocksPerScale, 256, 0, stream>>>(x, out, blocksPerScale);
}